// Round 2
// baseline (1239.894 us; speedup 1.0000x reference)
//
#include <hip/hip_runtime.h>

// Problem constants (from reference): WIDTH=64 -> S=4096, E=128, B=8,
// edges per batch = 32 paths * 16 edges = 512.
#define WIDTH 64
#define S 4096
#define E 128
#define BATCH 8
#define EDGES_PER_B 512
#define TOTAL_EDGES (BATCH * EDGES_PER_B)

// Fill geometry: grid is sized so FILL_THREADS == ATTN_N4 exactly.
// -> stride-pass 0 covers precisely the attn region (bp broadcast),
//    passes 1..64 cover the two A copies (zeros).
#define FILL_TPB 256
#define FILL_BLOCKS 4096
#define FILL_THREADS (FILL_BLOCKS * FILL_TPB)   // 1,048,576
#define ATTN_N4 (BATCH * S * (E / 4))           // 1,048,576 float4s (16 MB)
#define A_N4 (2 * BATCH * S * (S / 4))          // 67,108,864 float4s (1.07 GB)
#define TOTAL_N4 (ATTN_N4 + A_N4)               // 68,157,440

typedef float vfloat4 __attribute__((ext_vector_type(4)));

// Writes the entire 1.09 GB output: bp broadcast over attn, zeros over
// A1+A2. REGULAR stores (through L2), not nontemporal: nt 16B stores
// defeat L2 write-coalescing and suffer 4x HBM write amplification
// (WRITE_SIZE == 4x buffer on every fill-path dispatch; 1.6 TB/s useful).
// L2-routed stores merge a wave's 64x16B into full lines -> ~6.3 TB/s.
__global__ __launch_bounds__(FILL_TPB) void fill_out_kernel(
    float* __restrict__ out, const float* __restrict__ bp) {
    const int tid = blockIdx.x * FILL_TPB + threadIdx.x;  // 0..FILL_THREADS-1
    vfloat4* __restrict__ o = reinterpret_cast<vfloat4*>(out);

    // attn[b,s,e] = bp[e]: tid & 31 selects the float4 of bp this lane
    // needs; the grid stride (1,048,576) is a multiple of E/4 = 32 so
    // pass 0 covers exactly the attn region.
    o[tid] = reinterpret_cast<const vfloat4*>(bp)[tid & (E / 4 - 1)];

    const vfloat4 z = {0.f, 0.f, 0.f, 0.f};
    vfloat4* __restrict__ oz = o + ATTN_N4;
#pragma unroll 8
    for (int p = 0; p < A_N4 / FILL_THREADS; ++p)   // exactly 64 passes
        oz[tid + p * FILL_THREADS] = z;
}

// Mark first occurrence of each (src,dst) pair per batch.
// A.at[...].set(1.0) semantics: duplicate edges count ONCE in hidden.
__global__ void dedupe_kernel(const int* __restrict__ edges,
                              int* __restrict__ flags) {
    const int b = blockIdx.x;
    __shared__ int keys[EDGES_PER_B];
    const int4* eb = reinterpret_cast<const int4*>(edges) + b * EDGES_PER_B;
    for (int i = threadIdx.x; i < EDGES_PER_B; i += blockDim.x) {
        int4 e = eb[i];                 // [x0, y0, x1, y1]
        int src = e.y * WIDTH + e.x;    // node = y*WIDTH + x
        int dst = e.w * WIDTH + e.z;
        keys[i] = src * S + dst;
    }
    __syncthreads();
    for (int i = threadIdx.x; i < EDGES_PER_B; i += blockDim.x) {
        int k = keys[i];
        int uniq = 1;
        for (int j = 0; j < i; ++j) {
            if (keys[j] == k) { uniq = 0; break; }
        }
        flags[b * EDGES_PER_B + i] = uniq;
    }
}

// One block (128 threads) per edge:
//  - set A[b,src,dst] = 1 in both output copies
//  - if first occurrence: attn[b,src,:] += (values[b,dst,:]@Wv + bv) @ Wp
__global__ void scatter_kernel(const int* __restrict__ edges,
                               const int* __restrict__ flags,
                               const float* __restrict__ values,
                               const float* __restrict__ Wv,
                               const float* __restrict__ bv,
                               const float* __restrict__ Wp,
                               float* __restrict__ attn,
                               float* __restrict__ A1,
                               float* __restrict__ A2) {
    const int g = blockIdx.x;           // edge index, 0..4095
    const int b = g >> 9;               // / EDGES_PER_B
    int4 e = reinterpret_cast<const int4*>(edges)[g];
    const int src = e.y * WIDTH + e.x;
    const int dst = e.w * WIDTH + e.z;
    const int aidx = (b * S + src) * S + dst;   // < 2^27, fits int
    if (threadIdx.x == 0) A1[aidx] = 1.0f;
    if (threadIdx.x == 1) A2[aidx] = 1.0f;
    if (!flags[g]) return;              // block-uniform, safe

    __shared__ float sv[E];
    __shared__ float hv[E];
    const int t = threadIdx.x;
    sv[t] = values[(b * S + dst) * E + t];
    __syncthreads();
    float acc = bv[t];
#pragma unroll 8
    for (int k = 0; k < E; ++k) acc += sv[k] * Wv[k * E + t];
    hv[t] = acc;
    __syncthreads();
    float p = 0.0f;
#pragma unroll 8
    for (int k = 0; k < E; ++k) p += hv[k] * Wp[k * E + t];
    atomicAdd(&attn[(b * S + src) * E + t], p);
}

extern "C" void kernel_launch(void* const* d_in, const int* in_sizes, int n_in,
                              void* d_out, int out_size, void* d_ws,
                              size_t ws_size, hipStream_t stream) {
    // setup_inputs order:
    // 0 queries, 1 keys, 2 values, 3 oracle_edges, 4 Wq, 5 bq, 6 Wk, 7 bk,
    // 8 Wv, 9 bv, 10 Wp, 11 bp
    const float* values = (const float*)d_in[2];
    const int*   edges  = (const int*)d_in[3];
    const float* Wv     = (const float*)d_in[8];
    const float* bv     = (const float*)d_in[9];
    const float* Wp     = (const float*)d_in[10];
    const float* bp     = (const float*)d_in[11];

    float* out  = (float*)d_out;
    float* attn = out;                                  // [B,S,E]
    float* A1   = out + (size_t)BATCH * S * E;          // [B,S,S]
    float* A2   = A1 + (size_t)BATCH * S * S;           // [B,S,S] (copy)

    int* flags = (int*)d_ws;                            // 4096 ints

    // One kernel writes the whole 1.09 GB output through L2 (no nt, no
    // runtime fill path -> no 4x write amplification).
    fill_out_kernel<<<FILL_BLOCKS, FILL_TPB, 0, stream>>>(out, bp);

    dedupe_kernel<<<BATCH, 256, 0, stream>>>(edges, flags);
    scatter_kernel<<<TOTAL_EDGES, 128, 0, stream>>>(edges, flags, values, Wv,
                                                    bv, Wp, attn, A1, A2);
}

// Round 3
// 1154.867 us; speedup vs baseline: 1.0736x; 1.0736x over previous
//
#include <hip/hip_runtime.h>

// Problem constants (from reference): WIDTH=64 -> S=4096, E=128, B=8,
// edges per batch = 32 paths * 16 edges = 512.
#define WIDTH 64
#define S 4096
#define E 128
#define BATCH 8
#define EDGES_PER_B 512
#define TOTAL_EDGES (BATCH * EDGES_PER_B)

#define ATTN_FLOATS (BATCH * S * E)            // 4,194,304 floats (16.78 MB)
#define ATTN_N4 (ATTN_FLOATS / 4)              // 1,048,576 float4s

typedef float vfloat4 __attribute__((ext_vector_type(4)));

// ---------------------------------------------------------------------------
// Workspace-accumulation path. Key finding of rounds 0-2: d_out behaves as
// uncached memory — every 16B store is its own 64B HBM burst (WRITE_SIZE is
// exactly 4x useful bytes on the rocclr fill, and our own fills — nt or
// L2-routed — all run at the same ~1.5 TB/s useful). The A-region zeroing
// therefore floors at ~690 us (rocclr memset already achieves it).
// This round removes all FINE-GRAINED traffic to d_out: accumulate attn in
// cached workspace, then stream it out once.
// ---------------------------------------------------------------------------

// Zero the ws attn accumulator (16 MB, cached memory -> fast).
__global__ __launch_bounds__(256) void zero_ws_kernel(float* __restrict__ ws) {
    const int i = blockIdx.x * 256 + threadIdx.x;      // grid covers ATTN_N4
    const vfloat4 z = {0.f, 0.f, 0.f, 0.f};
    reinterpret_cast<vfloat4*>(ws)[i] = z;
}

// Mark first occurrence of each (src,dst) pair per batch.
// A.at[...].set(1.0) semantics: duplicate edges count ONCE in hidden.
__global__ void dedupe_kernel(const int* __restrict__ edges,
                              int* __restrict__ flags) {
    const int b = blockIdx.x;
    __shared__ int keys[EDGES_PER_B];
    const int4* eb = reinterpret_cast<const int4*>(edges) + b * EDGES_PER_B;
    for (int i = threadIdx.x; i < EDGES_PER_B; i += blockDim.x) {
        int4 e = eb[i];                 // [x0, y0, x1, y1]
        int src = e.y * WIDTH + e.x;    // node = y*WIDTH + x
        int dst = e.w * WIDTH + e.z;
        keys[i] = src * S + dst;
    }
    __syncthreads();
    for (int i = threadIdx.x; i < EDGES_PER_B; i += blockDim.x) {
        int k = keys[i];
        int uniq = 1;
        for (int j = 0; j < i; ++j) {
            if (keys[j] == k) { uniq = 0; break; }
        }
        flags[b * EDGES_PER_B + i] = uniq;
    }
}

// One block (128 threads) per edge: if first occurrence,
// ws_attn[b,src,:] += (values[b,dst,:]@Wv + bv) @ Wp.  Atomics land in
// CACHED workspace, not the uncached output.
__global__ void scatter_ws_kernel(const int* __restrict__ edges,
                                  const int* __restrict__ flags,
                                  const float* __restrict__ values,
                                  const float* __restrict__ Wv,
                                  const float* __restrict__ bv,
                                  const float* __restrict__ Wp,
                                  float* __restrict__ ws_attn) {
    const int g = blockIdx.x;           // edge index, 0..4095
    if (!flags[g]) return;              // block-uniform, safe
    const int b = g >> 9;               // / EDGES_PER_B
    int4 e = reinterpret_cast<const int4*>(edges)[g];
    const int src = e.y * WIDTH + e.x;
    const int dst = e.w * WIDTH + e.z;

    __shared__ float sv[E];
    __shared__ float hv[E];
    const int t = threadIdx.x;
    sv[t] = values[(b * S + dst) * E + t];
    __syncthreads();
    float acc = bv[t];
#pragma unroll 8
    for (int k = 0; k < E; ++k) acc += sv[k] * Wv[k * E + t];
    hv[t] = acc;
    __syncthreads();
    float p = 0.0f;
#pragma unroll 8
    for (int k = 0; k < E; ++k) p += hv[k] * Wp[k * E + t];
    atomicAdd(&ws_attn[(b * S + src) * E + t], p);
}

// Stream attn out once: attn[b,s,:] = bp[:] + ws_attn[b,s,:].
__global__ __launch_bounds__(256) void compose_attn_kernel(
    float* __restrict__ attn, const float* __restrict__ ws_attn,
    const float* __restrict__ bp) {
    const int i = blockIdx.x * 256 + threadIdx.x;      // grid covers ATTN_N4
    const vfloat4 a = reinterpret_cast<const vfloat4*>(ws_attn)[i];
    const vfloat4 b = reinterpret_cast<const vfloat4*>(bp)[i & (E / 4 - 1)];
    reinterpret_cast<vfloat4*>(attn)[i] = a + b;
}

// Write the 1.0 entries into both A copies (after the memset).
__global__ __launch_bounds__(256) void ones_kernel(const int* __restrict__ edges,
                                                   float* __restrict__ A1,
                                                   float* __restrict__ A2) {
    const int g = blockIdx.x * 256 + threadIdx.x;      // 0..TOTAL_EDGES-1
    int4 e = reinterpret_cast<const int4*>(edges)[g];
    const int b = g >> 9;
    const int src = e.y * WIDTH + e.x;
    const int dst = e.w * WIDTH + e.z;
    const int aidx = (b * S + src) * S + dst;
    A1[aidx] = 1.0f;
    A2[aidx] = 1.0f;
}

// ---------------------------------------------------------------------------
// Fallback (round-0 behavior) if workspace is too small for the accumulator.
// ---------------------------------------------------------------------------
__global__ void init_attn_kernel(float* __restrict__ attn,
                                 const float* __restrict__ bp) {
    const int i = blockIdx.x * blockDim.x + threadIdx.x;
    const int e0 = (i * 4) & (E - 1);
    vfloat4 v = {bp[e0], bp[e0 + 1], bp[e0 + 2], bp[e0 + 3]};
    reinterpret_cast<vfloat4*>(attn)[i] = v;
}

__global__ void scatter_kernel(const int* __restrict__ edges,
                               const int* __restrict__ flags,
                               const float* __restrict__ values,
                               const float* __restrict__ Wv,
                               const float* __restrict__ bv,
                               const float* __restrict__ Wp,
                               float* __restrict__ attn,
                               float* __restrict__ A1,
                               float* __restrict__ A2) {
    const int g = blockIdx.x;
    const int b = g >> 9;
    int4 e = reinterpret_cast<const int4*>(edges)[g];
    const int src = e.y * WIDTH + e.x;
    const int dst = e.w * WIDTH + e.z;
    const int aidx = (b * S + src) * S + dst;
    if (threadIdx.x == 0) A1[aidx] = 1.0f;
    if (threadIdx.x == 1) A2[aidx] = 1.0f;
    if (!flags[g]) return;

    __shared__ float sv[E];
    __shared__ float hv[E];
    const int t = threadIdx.x;
    sv[t] = values[(b * S + dst) * E + t];
    __syncthreads();
    float acc = bv[t];
#pragma unroll 8
    for (int k = 0; k < E; ++k) acc += sv[k] * Wv[k * E + t];
    hv[t] = acc;
    __syncthreads();
    float p = 0.0f;
#pragma unroll 8
    for (int k = 0; k < E; ++k) p += hv[k] * Wp[k * E + t];
    atomicAdd(&attn[(b * S + src) * E + t], p);
}

extern "C" void kernel_launch(void* const* d_in, const int* in_sizes, int n_in,
                              void* d_out, int out_size, void* d_ws,
                              size_t ws_size, hipStream_t stream) {
    // setup_inputs order:
    // 0 queries, 1 keys, 2 values, 3 oracle_edges, 4 Wq, 5 bq, 6 Wk, 7 bk,
    // 8 Wv, 9 bv, 10 Wp, 11 bp
    const float* values = (const float*)d_in[2];
    const int*   edges  = (const int*)d_in[3];
    const float* Wv     = (const float*)d_in[8];
    const float* bv     = (const float*)d_in[9];
    const float* Wp     = (const float*)d_in[10];
    const float* bp     = (const float*)d_in[11];

    float* out  = (float*)d_out;
    float* attn = out;                                  // [B,S,E]
    float* A1   = out + (size_t)BATCH * S * E;          // [B,S,S]
    float* A2   = A1 + (size_t)BATCH * S * S;           // [B,S,S] (copy)

    // A-region zeroing: rocclr fill already sits on the uncached-output
    // write floor (~690 us for 4x-amplified 1.073 GB). Keep it.
    (void)hipMemsetAsync(A1, 0, (size_t)2 * BATCH * S * S * sizeof(float),
                         stream);

    const size_t ws_needed =
        (size_t)ATTN_FLOATS * sizeof(float) + TOTAL_EDGES * sizeof(int);

    if (ws_size >= ws_needed) {
        float* ws_attn = (float*)d_ws;                  // 16.78 MB, cached
        int*   flags   = (int*)(ws_attn + ATTN_FLOATS); // 16 KB

        zero_ws_kernel<<<ATTN_N4 / 256, 256, 0, stream>>>(ws_attn);
        dedupe_kernel<<<BATCH, 256, 0, stream>>>(edges, flags);
        scatter_ws_kernel<<<TOTAL_EDGES, 128, 0, stream>>>(
            edges, flags, values, Wv, bv, Wp, ws_attn);
        compose_attn_kernel<<<ATTN_N4 / 256, 256, 0, stream>>>(attn, ws_attn,
                                                               bp);
        ones_kernel<<<TOTAL_EDGES / 256, 256, 0, stream>>>(edges, A1, A2);
    } else {
        // Fallback: round-0 path (atomics directly into output).
        int* flags = (int*)d_ws;
        init_attn_kernel<<<ATTN_N4 / 256, 256, 0, stream>>>(attn, bp);
        dedupe_kernel<<<BATCH, 256, 0, stream>>>(edges, flags);
        scatter_kernel<<<TOTAL_EDGES, 128, 0, stream>>>(
            edges, flags, values, Wv, bv, Wp, attn, A1, A2);
    }
}